// Round 27
// baseline (534.558 us; speedup 1.0000x reference)
//
#include <hip/hip_runtime.h>
#include <hip/hip_bf16.h>
#include <math.h>

typedef __attribute__((ext_vector_type(8))) short bf16x8;
typedef __attribute__((ext_vector_type(4))) float f32x4;
typedef __attribute__((ext_vector_type(4))) float f4;
typedef __attribute__((ext_vector_type(8))) unsigned short us8;
typedef __attribute__((ext_vector_type(4))) unsigned short us4;
typedef unsigned short u16;
typedef unsigned int u32;

#define HEADS 8
#define SHIFT_ 3
#define HIMG 56
#define WIMG 56
#define WA 49
#define NTOK 100352
#define NPAIR 16384

static __device__ __forceinline__ float bf2f(u16 v){ return __uint_as_float(((u32)v)<<16); }
static __device__ __forceinline__ u16 f2bf(float f){
  u32 u = __float_as_uint(f);
  return (u16)((u + 0x7fffu + ((u>>16)&1u)) >> 16);
}
static __device__ __forceinline__ u32 pkbf(float a, float b){
  __hip_bfloat162 h = __float22bfloat162_rn(make_float2(a, b));
  return *reinterpret_cast<u32*>(&h);
}
static __device__ __forceinline__ float wsum(float v){
  #pragma unroll
  for (int off=32; off>0; off>>=1) v += __shfl_xor(v, off, 64);
  return v;
}
static __device__ __forceinline__ void glds16(const u16* g, u16* l){
  __builtin_amdgcn_global_load_lds(
      (const __attribute__((address_space(1))) unsigned int*)g,
      (__attribute__((address_space(3))) unsigned int*)l, 16, 0, 0);
}
static __device__ __forceinline__ int tok2pix(int row){
  int bw = row / 49, t = row - bw*49;
  int b  = bw >> 6,  w = bw & 63;
  int wh = w >> 3,   ww = w & 7;
  int th = t / 7,    tw = t - th*7;
  int r = wh*7 + th + SHIFT_; if (r >= HIMG) r -= HIMG;
  int c = ww*7 + tw + SHIFT_; if (c >= WIMG) c -= WIMG;
  return (b*HIMG + r)*WIMG + c;
}
static __device__ __forceinline__ float gelu_f(float x){
  float e = __expf(-1.702f*x);
  return x*__builtin_amdgcn_rcpf(1.0f+e);
}

template<int C, int ISBF>
__global__ void ln_stats_kernel(const void* __restrict__ srcv, float* __restrict__ stats){
  int wave = threadIdx.x >> 6, lane = threadIdx.x & 63;
  int tok = blockIdx.x*4 + wave;
  float s=0.f, s2=0.f;
  if (ISBF == 0){
    const float* p = (const float*)srcv + (size_t)tok*C;
    #pragma unroll
    for (int i=0;i<C/256;i++){
      f4 v = *(const f4*)(p + lane*4*(C/256) + i*4);
      #pragma unroll
      for (int e=0;e<4;e++){ float f=v[e]; s+=f; s2+=f*f; }
    }
  } else {
    const u16* p = (const u16*)srcv + (size_t)tok*C;
    #pragma unroll
    for (int i=0;i<C/512;i++){
      us8 v = *(const us8*)(p + lane*8*(C/512) + i*8);
      #pragma unroll
      for (int e=0;e<8;e++){ float f=bf2f(v[e]); s+=f; s2+=f*f; }
    }
  }
  s = wsum(s); s2 = wsum(s2);
  if (lane==0){
    float mean = s/(float)C;
    float var  = s2/(float)C - mean*mean;
    stats[2*tok]   = mean;
    stats[2*tok+1] = rsqrtf(var + 1e-5f);
  }
}

__global__ void ln_apply_kernel(const float* __restrict__ src, u16* __restrict__ dst){
  int wave = threadIdx.x >> 6, lane = threadIdx.x & 63;
  int tok = blockIdx.x*4 + wave;
  const float* p = src + (size_t)tok*256;
  f4 a = *(const f4*)(p + lane*4);
  float s = a[0]+a[1]+a[2]+a[3];
  float s2 = a[0]*a[0]+a[1]*a[1]+a[2]*a[2]+a[3]*a[3];
  s = wsum(s); s2 = wsum(s2);
  float mean = s*(1.f/256.f);
  float var  = s2*(1.f/256.f) - mean*mean;
  float rstd = rsqrtf(var + 1e-5f);
  u32 o2[2];
  o2[0] = pkbf((a[0]-mean)*rstd, (a[1]-mean)*rstd);
  o2[1] = pkbf((a[2]-mean)*rstd, (a[3]-mean)*rstd);
  *(u32*)(dst + (size_t)tok*256 + lane*4)     = o2[0];
  *(u32*)(dst + (size_t)tok*256 + lane*4 + 2) = o2[1];
}

__global__ void ln_apply_b_kernel(const u16* __restrict__ src, u16* __restrict__ dst,
                                  float* __restrict__ st){
  int wave = threadIdx.x >> 6, lane = threadIdx.x & 63;
  int tok = blockIdx.x*4 + wave;
  const u16* p = src + (size_t)tok*256 + lane*4;
  us4 a4 = *(const us4*)p;
  float a0=bf2f(a4[0]), a1=bf2f(a4[1]), a2=bf2f(a4[2]), a3=bf2f(a4[3]);
  float s = a0+a1+a2+a3;
  float s2 = a0*a0+a1*a1+a2*a2+a3*a3;
  s = wsum(s); s2 = wsum(s2);
  float mean = s*(1.f/256.f);
  float var  = s2*(1.f/256.f) - mean*mean;
  float rstd = rsqrtf(var + 1e-5f);
  u32 o0 = pkbf((a0-mean)*rstd, (a1-mean)*rstd);
  u32 o1 = pkbf((a2-mean)*rstd, (a3-mean)*rstd);
  u16* d = dst + (size_t)tok*256 + lane*4;
  *(u32*)d     = o0;
  *(u32*)(d+2) = o1;
  if (lane==0){ st[2*tok] = mean; st[2*tok+1] = rstd; }
}

__global__ void cmb_kernel(const float* __restrict__ rpb, const int* __restrict__ rel,
                           const float* __restrict__ mask, u16* __restrict__ cmb){
  int lin = blockIdx.x*1024 + threadIdx.x*4;
  int j0 = lin & 63;
  int r3 = lin >> 6;
  int i  = r3 % 49;
  int wh = r3 / 49;
  int h = wh & 7, w = wh >> 3;
  us4 o;
  #pragma unroll
  for (int e=0;e<4;e++){
    int j = j0 + e;
    float v = 0.f;
    if (j < WA) v = rpb[rel[i*WA+j]*8 + h] + mask[((size_t)w*WA + i)*WA + j];
    o[e] = f2bf(v);
  }
  *(us4*)(cmb + lin) = o;
}

__global__ void prep_weights(
    const float* __restrict__ qkv_w, const float* __restrict__ qkv_b,
    const float* __restrict__ ln1w,  const float* __restrict__ ln1b,
    const float* __restrict__ fc1_w, const float* __restrict__ fc1_b,
    const float* __restrict__ ln2w,  const float* __restrict__ ln2b,
    const float* __restrict__ fc2_w, const float* __restrict__ fc2_b,
    const float* __restrict__ ln3w,  const float* __restrict__ ln3b,
    const float* __restrict__ proj_w, const float* __restrict__ proj_b,
    u16* __restrict__ wq, float* __restrict__ bq,
    u16* __restrict__ w1, float* __restrict__ b1,
    u16* __restrict__ w2, float* __restrict__ b2,
    u16* __restrict__ wp, float* __restrict__ bp,
    float* __restrict__ cs2, float* __restrict__ hstats)
{
  for (int idx = blockIdx.x*256 + threadIdx.x; idx < 2*NTOK; idx += gridDim.x*256)
    hstats[idx] = 0.f;

  int wave = threadIdx.x>>6, lane = threadIdx.x&63;
  int n = blockIdx.x*4 + wave;
  const float *W,*lw,*lb,*bs; u16* WO; float* BO; int K, row, noln, docs;
  float qs = 1.f;
  if (n < 768)      { W=qkv_w; lw=ln1w; lb=ln1b; bs=qkv_b; WO=wq; BO=bq; K=256;  row=n;      noln=0; docs=0;
                      if (n < 256) qs = 0.17677669529663689f; }
  else if (n < 1792){ W=fc1_w; lw=ln2w; lb=ln2b; bs=fc1_b; WO=w1; BO=b1; K=256;  row=n-768;  noln=0; docs=0; }
  else if (n < 2048){ W=fc2_w; lw=ln3w; lb=ln3b; bs=fc2_b; WO=w2; BO=b2; K=1024; row=n-1792; noln=0; docs=1; }
  else              { W=proj_w; lw=nullptr; lb=nullptr; bs=proj_b; WO=wp; BO=bp; K=256; row=n-2048; noln=1; docs=0; }
  float dot = 0.f, cs = 0.f;
  for (int k=lane; k<K; k+=64){
    float wv = W[(size_t)row*K + k];
    if (noln){
      WO[(size_t)row*K + k] = f2bf(wv);
    } else {
      dot += wv * lb[k];
      u16 q = f2bf(wv * lw[k] * qs);
      WO[(size_t)row*K + k] = q;
      cs += bf2f(q);
    }
  }
  dot = wsum(dot);
  if (docs){ cs = wsum(cs); if (lane==0) cs2[row] = cs; }
  if (lane==0) BO[row] = (bs[row] + dot) * qs;
}

template<int SMODE, int EPI, int SWAP, int DEPTH>
__global__ __launch_bounds__(256)
void gemm18(const void* __restrict__ Av, const u16* __restrict__ Bt,
            const float* __restrict__ stats, float* __restrict__ hstats,
            const float* __restrict__ biasf, const float* __restrict__ resid,
            const float* __restrict__ colsum, void* __restrict__ outv,
            int K, int NT, int CHUNK)
{
  constexpr int BM=128, BN=128, BK=32;
  constexpr int NBUF = DEPTH + 1;
  __shared__ u16 smem[NBUF*8192];
  constexpr int BOFF = NBUF*4096;
  int b = blockIdx.x;
  int linear = (b & 7)*CHUNK + (b >> 3);
  int mt = linear / NT, nt = linear - mt*NT;
  int m0 = mt*BM, n0 = nt*BN;
  int tid  = threadIdx.x;
  int lane = tid & 63, wave = tid >> 6;
  int wr = wave >> 1, wc = wave & 1;
  int lc16 = lane & 15, g = lane >> 4;
  int nsteps = K >> 5;

  const u16* asrc[2];
  const u16* bsrc[2];
  #pragma unroll
  for (int i=0;i<2;i++){
    int c = tid + i*256;
    int row = c >> 2, gch = ((c & 3) - (row >> 1)) & 3;
    if (SMODE <= 1){
      int grow = (SMODE==0) ? tok2pix(m0+row) : (m0+row);
      asrc[i] = (const u16*)Av + (size_t)grow*K + gch*8;
    }
    bsrc[i] = Bt + (size_t)(n0+row)*K + gch*8;
  }
  float smean[2], srstd[2];
  if (SMODE == 3){
    #pragma unroll
    for (int i=0;i<2;i++){
      int grow = m0 + ((tid + i*256) >> 2);
      smean[i] = stats[2*grow]; srstd[i] = stats[2*grow+1];
    }
  }

  f32x4 acc[4][4];
  #pragma unroll
  for (int i=0;i<4;i++)
    #pragma unroll
    for (int j=0;j<4;j++){ acc[i][j][0]=0.f; acc[i][j][1]=0.f; acc[i][j][2]=0.f; acc[i][j][3]=0.f; }

  if (SMODE <= 1){
    #pragma unroll
    for (int pt=0; pt<DEPTH; ++pt){
      int kt = pt << 5;
      #pragma unroll
      for (int i=0;i<2;i++) glds16(asrc[i]+kt, smem + pt*4096 + i*2048 + wave*512);
      #pragma unroll
      for (int i=0;i<2;i++) glds16(bsrc[i]+kt, smem + BOFF + pt*4096 + i*2048 + wave*512);
    }
    asm volatile("s_waitcnt vmcnt(4)" ::: "memory");
    __builtin_amdgcn_s_barrier();

    int cur = 0;
    for (int t=0; t<nsteps; ++t){
      if (t+DEPTH < nsteps){
        int ktD = (t+DEPTH) << 5;
        int nb = cur + DEPTH; if (nb >= NBUF) nb -= NBUF;
        int off = nb*4096;
        #pragma unroll
        for (int i=0;i<2;i++) glds16(asrc[i]+ktD, smem + off + i*2048 + wave*512);
        #pragma unroll
        for (int i=0;i<2;i++) glds16(bsrc[i]+ktD, smem + BOFF + off + i*2048 + wave*512);
      }
      const u16* Ap = smem + cur*4096;
      const u16* Bp = smem + BOFF + cur*4096;
      bf16x8 af[4], bfr[4];
      #pragma unroll
      for (int mi=0;mi<4;mi++){
        int r = wr*64 + mi*16 + lc16;
        u32 byte = (u32)(r*64) + ((u32)((g + (r>>1)) & 3) << 4);
        af[mi] = *(const bf16x8*)(Ap + (byte>>1));
      }
      #pragma unroll
      for (int ni=0;ni<4;ni++){
        int r = wc*64 + ni*16 + lc16;
        u32 byte = (u32)(r*64) + ((u32)((g + (r>>1)) & 3) << 4);
        bfr[ni] = *(const bf16x8*)(Bp + (byte>>1));
      }
      #pragma unroll
      for (int mi=0;mi<4;mi++)
        #pragma unroll
        for (int ni=0;ni<4;ni++)
          acc[mi][ni] = SWAP ? __builtin_amdgcn_mfma_f32_16x16x32_bf16(bfr[ni], af[mi], acc[mi][ni], 0, 0, 0)
                             : __builtin_amdgcn_mfma_f32_16x16x32_bf16(af[mi], bfr[ni], acc[mi][ni], 0, 0, 0);
      int rem = nsteps - 1 - t;
      int cnt = (rem < DEPTH) ? rem : DEPTH;
      if (cnt >= 2)      asm volatile("s_waitcnt vmcnt(4)" ::: "memory");
      else if (cnt == 1) asm volatile("s_waitcnt vmcnt(0)" ::: "memory");
      __builtin_amdgcn_s_barrier();
      cur = (cur+1 == NBUF) ? 0 : cur+1;
    }
  } else {
    f4 rcurf[2][2];
    #pragma unroll
    for (int i=0;i<2;i++){
      int c = tid + i*256; int row = c>>2, gch = ((c&3) - (row>>1)) & 3;
      const float* ap = (const float*)Av + (size_t)(m0+row)*K + gch*8;
      rcurf[i][0] = *(const f4*)ap; rcurf[i][1] = *(const f4*)(ap+4);
    }
    for (int t=0; t<nsteps; ++t){
      int kt = t << 5;
      #pragma unroll
      for (int i=0;i<2;i++){
        int c = tid + i*256; int row = c>>2, s = c&3;
        us8 o;
        #pragma unroll
        for (int e=0;e<8;e++){
          float fv = rcurf[i][e>>2][e&3];
          o[e] = f2bf((fv - smean[i])*srstd[i]);
        }
        u32 byte = (u32)(row*64) + ((u32)s << 4);
        *(us8*)(smem + (byte>>1)) = o;
      }
      #pragma unroll
      for (int i=0;i<2;i++) glds16(bsrc[i]+kt, smem + BOFF + i*2048 + wave*512);
      __syncthreads();
      if (t+1 < nsteps){
        int kt1 = kt + 32;
        #pragma unroll
        for (int i=0;i<2;i++){
          int c = tid + i*256; int row = c>>2, gch = ((c&3) - (row>>1)) & 3;
          const float* ap = (const float*)Av + (size_t)(m0+row)*K + kt1 + gch*8;
          rcurf[i][0] = *(const f4*)ap; rcurf[i][1] = *(const f4*)(ap+4);
        }
      }
      bf16x8 af[4], bfr[4];
      #pragma unroll
      for (int mi=0;mi<4;mi++){
        int r = wr*64 + mi*16 + lc16;
        u32 byte = (u32)(r*64) + ((u32)((g + (r>>1)) & 3) << 4);
        af[mi] = *(const bf16x8*)(smem + (byte>>1));
      }
      #pragma unroll
      for (int ni=0;ni<4;ni++){
        int r = wc*64 + ni*16 + lc16;
        u32 byte = (u32)(r*64) + ((u32)((g + (r>>1)) & 3) << 4);
        bfr[ni] = *(const bf16x8*)(smem + BOFF + (byte>>1));
      }
      #pragma unroll
      for (int mi=0;mi<4;mi++)
        #pragma unroll
        for (int ni=0;ni<4;ni++)
          acc[mi][ni] = SWAP ? __builtin_amdgcn_mfma_f32_16x16x32_bf16(bfr[ni], af[mi], acc[mi][ni], 0, 0, 0)
                             : __builtin_amdgcn_mfma_f32_16x16x32_bf16(af[mi], bfr[ni], acc[mi][ni], 0, 0, 0);
      __syncthreads();
    }
  }

  int lr = lane >> 4;
  if (EPI==0){
    u16* Cs = smem;
    #pragma unroll
    for (int mi=0;mi<4;mi++){
      #pragma unroll
      for (int ni=0;ni<4;ni++){
        int cl = wc*64 + ni*16 + lc16;
        float bv = biasf[n0 + cl];
        #pragma unroll
        for (int j=0;j<4;j++){
          int rl = wr*64 + mi*16 + lr*4 + j;
          float v = acc[mi][ni][j] + bv;
          u32 byte = (u32)(rl*256 + cl*2) ^ ((u32)(rl&7)<<4);
          Cs[byte>>1] = f2bf(v);
        }
      }
    }
    __syncthreads();
    #pragma unroll
    for (int i=0;i<8;i++){
      int c = tid + i*256;
      int rl = c>>4, c0 = (c&15)*8;
      u32 byte = (u32)(rl*256 + c0*2) ^ ((u32)(rl&7)<<4);
      us8 v = *(const us8*)(Cs + (byte>>1));
      int row = m0 + rl, col = n0 + c0;
      int which = col>>8, hh = (col>>5)&7, d0 = col&31;
      int bwi = row/49, t = row - bwi*49;
      *(us8*)((u16*)outv + ((size_t)which*NPAIR + bwi*8 + hh)*(WA*32) + t*32 + d0) = v;
    }
  } else if (EPI==5){
    u16* Cs = smem;
    #pragma unroll
    for (int mi=0;mi<4;mi++){
      int rl = wr*64 + mi*16 + lc16;
      int pix = tok2pix(m0 + rl);
      #pragma unroll
      for (int ni=0;ni<4;ni++){
        int cl = wc*64 + ni*16 + g*4;
        int col = n0 + cl;
        f4 bv = *(const f4*)(biasf + col);
        f4 rr = *(const f4*)(resid + (size_t)pix*256 + col);
        float v0 = acc[mi][ni][0] + bv[0] + rr[0];
        float v1 = acc[mi][ni][1] + bv[1] + rr[1];
        float v2 = acc[mi][ni][2] + bv[2] + rr[2];
        float v3 = acc[mi][ni][3] + bv[3] + rr[3];
        u32 w0 = pkbf(v0, v1), w1 = pkbf(v2, v3);
        u32 byte = (u32)(rl*256 + cl*2) ^ ((u32)(rl&7)<<4);
        *(u32*)(Cs + (byte>>1))     = w0;
        *(u32*)(Cs + (byte>>1) + 2) = w1;
      }
    }
    __syncthreads();
    #pragma unroll
    for (int i=0;i<8;i++){
      int c = tid + i*256;
      int rl = c>>4, c0 = (c&15)*8;
      u32 byte = (u32)(rl*256 + c0*2) ^ ((u32)(rl&7)<<4);
      us8 v = *(const us8*)(Cs + (byte>>1));
      int pix = tok2pix(m0 + rl);
      *(us8*)((u16*)outv + (size_t)pix*256 + n0 + c0) = v;
    }
  } else if (EPI==2){
    u16* Cs = smem;
    #pragma unroll
    for (int mi=0;mi<4;mi++){
      int rl = wr*64 + mi*16 + lc16;
      float ss = 0.f, sq = 0.f;
      #pragma unroll
      for (int ni=0;ni<4;ni++){
        int cl = wc*64 + ni*16 + g*4;
        f4 bv = *(const f4*)(biasf + n0 + cl);
        float v0 = gelu_f(acc[mi][ni][0] + bv[0]);
        float v1 = gelu_f(acc[mi][ni][1] + bv[1]);
        float v2 = gelu_f(acc[mi][ni][2] + bv[2]);
        float v3 = gelu_f(acc[mi][ni][3] + bv[3]);
        ss += (v0+v1)+(v2+v3);
        sq += (v0*v0+v1*v1)+(v2*v2+v3*v3);
        u32 w0 = pkbf(v0, v1), w1 = pkbf(v2, v3);
        u32 byte = (u32)(rl*256 + cl*2) ^ ((u32)(rl&7)<<4);
        *(u32*)(Cs + (byte>>1))     = w0;
        *(u32*)(Cs + (byte>>1) + 2) = w1;
      }
      ss += __shfl_xor(ss, 16, 64); ss += __shfl_xor(ss, 32, 64);
      sq += __shfl_xor(sq, 16, 64); sq += __shfl_xor(sq, 32, 64);
      if (g==0){
        int grow = m0 + rl;
        atomicAdd(&hstats[2*grow],   ss);
        atomicAdd(&hstats[2*grow+1], sq);
      }
    }
    __syncthreads();
    #pragma unroll
    for (int i=0;i<8;i++){
      int c = tid + i*256;
      int rl = c>>4, c0 = (c&15)*8;
      u32 byte = (u32)(rl*256 + c0*2) ^ ((u32)(rl&7)<<4);
      us8 v = *(const us8*)(Cs + (byte>>1));
      int row = m0 + rl, col = n0 + c0;
      *(us8*)((u16*)outv + (size_t)row*1024 + col) = v;
    }
  } else {
    #pragma unroll
    for (int mi=0;mi<4;mi++){
      int rl = wr*64 + mi*16 + lc16;
      int grow = m0 + rl;
      float rs = 1.f, mr = 0.f, istd2 = 0.f, mean2 = 0.f;
      if (EPI==4 || EPI==6){
        float s = stats[2*grow], q = stats[2*grow+1];
        float mean = s*(1.f/1024.f);
        float var  = q*(1.f/1024.f) - mean*mean;
        rs = rsqrtf(var + 1e-5f);
        mr = mean*rs;
      }
      if (EPI==6){
        mean2 = hstats[2*grow];
        istd2 = __builtin_amdgcn_rcpf(hstats[2*grow+1]);
      }
      size_t rowbase = (EPI==1) ? (size_t)tok2pix(grow)*256 : (size_t)grow*256;
      #pragma unroll
      for (int ni=0;ni<4;ni++){
        int col = n0 + wc*64 + ni*16 + g*4;
        f4 bv = *(const f4*)(biasf + col);
        f4 v;
        if (EPI==4 || EPI==6){
          f4 cw = *(const f4*)(colsum + col);
          #pragma unroll
          for (int j=0;j<4;j++) v[j] = acc[mi][ni][j]*rs - mr*cw[j] + bv[j];
        } else {
          #pragma unroll
          for (int j=0;j<4;j++) v[j] = acc[mi][ni][j] + bv[j];
        }
        if (EPI==6){
          us4 xr = *(const us4*)((const u16*)resid + rowbase + col);
          #pragma unroll
          for (int j=0;j<4;j++) v[j] += bf2f(xr[j])*istd2 + mean2;
        } else {
          f4 rr = *(const f4*)(resid + rowbase + col);
          v += rr;
        }
        *(f4*)((float*)outv + rowbase + col) = v;
      }
    }
  }
}

template<int EPI>
__global__ __launch_bounds__(512)
void gemm19(const u16* __restrict__ Av, const u16* __restrict__ Bt,
            const float* __restrict__ stats, float* __restrict__ st2,
            const float* __restrict__ biasf, const u16* __restrict__ residb,
            const float* __restrict__ colsum, void* __restrict__ outv,
            int K, int NT, int CHUNK)
{
  constexpr int BM=256, BN=128, BK=32;
  __shared__ u16 smem[36864];
  int b = blockIdx.x;
  int linear = (b & 7)*CHUNK + (b >> 3);
  int mt = linear / NT, nt = linear - mt*NT;
  int m0 = mt*BM, n0 = nt*BN;
  int tid  = threadIdx.x;
  int lane = tid & 63, wave = tid >> 6;
  int wr = wave >> 1, wc = wave & 1;
  int lc16 = lane & 15, g = lane >> 4;
  int nsteps = K >> 5;

  const u16* asrc[2];
  #pragma unroll
  for (int i=0;i<2;i++){
    int c = tid + i*512;
    int row = c >> 2, gch = ((c & 3) - (row >> 1)) & 3;
    asrc[i] = Av + (size_t)(m0+row)*K + gch*8;
  }
  const u16* bsrc0;
  {
    int row = tid >> 2, gch = ((tid & 3) - (row >> 1)) & 3;
    bsrc0 = Bt + (size_t)(n0+row)*K + gch*8;
  }

  f32x4 acc[4][4];
  #pragma unroll
  for (int i=0;i<4;i++)
    #pragma unroll
    for (int j=0;j<4;j++){ acc[i][j][0]=0.f; acc[i][j][1]=0.f; acc[i][j][2]=0.f; acc[i][j][3]=0.f; }

  #pragma unroll
  for (int pt=0; pt<2; ++pt){
    int kt = pt << 5;
    #pragma unroll
    for (int i=0;i<2;i++) glds16(asrc[i]+kt, smem + pt*8192 + i*4096 + wave*512);
    glds16(bsrc0+kt, smem + 24576 + pt*4096 + wave*512);
  }
  asm volatile("s_waitcnt vmcnt(3)" ::: "memory");
  __builtin_amdgcn_s_barrier();

  int cur = 0;
  for (int t=0; t<nsteps; ++t){
    if (t+2 < nsteps){
      int kt2 = (t+2) << 5;
      int nb = cur + 2; if (nb >= 3) nb -= 3;
      #pragma unroll
      for (int i=0;i<2;i++) glds16(asrc[i]+kt2, smem + nb*8192 + i*4096 + wave*512);
      glds16(bsrc0+kt2, smem + 24576 + nb*4096 + wave*512);
    }
    const u16* Ap = smem + cur*8192;
    const u16* Bp = smem + 24576 + cur*4096;
    bf16x8 af[4], bfr[4];
    #pragma unroll
    for (int mi=0;mi<4;mi++){
      int r = wr*64 + mi*16 + lc16;
      u32 byte = (u32)(r*64) + ((u32)((g + (r>>1)) & 3) << 4);
      af[mi] = *(const bf16x8*)(Ap + (byte>>1));
    }
    #pragma unroll
    for (int ni=0;ni<4;ni++){
      int r = wc*64 + ni*16 + lc16;
      u32 byte = (u32)(r*64) + ((u32)((g + (r>>1)) & 3) << 4);
      bfr[ni] = *(const bf16x8*)(Bp + (byte>>1));
    }
    #pragma unroll
    for (int mi=0;mi<4;mi++)
      #pragma unroll
      for (int ni=0;ni<4;ni++)
        acc[mi][ni] = __builtin_amdgcn_mfma_f32_16x16x32_bf16(bfr[ni], af[mi], acc[mi][ni], 0, 0, 0);
    int rem = nsteps - 1 - t;
    int cnt = (rem < 2) ? rem : 2;
    if (cnt == 2)      asm volatile("s_waitcnt vmcnt(3)" ::: "memory");
    else if (cnt == 1) asm volatile("s_waitcnt vmcnt(0)" ::: "memory");
    __builtin_amdgcn_s_barrier();
    cur = (cur+1 == 3) ? 0 : cur+1;
  }

  if (EPI==2){
    u16* Cs = smem;
    #pragma unroll
    for (int mi=0;mi<4;mi++){
      int rl = wr*64 + mi*16 + lc16;
      float ss = 0.f, sq = 0.f;
      #pragma unroll
      for (int ni=0;ni<4;ni++){
        int cl = wc*64 + ni*16 + g*4;
        f4 bv = *(const f4*)(biasf + n0 + cl);
        float v0 = gelu_f(acc[mi][ni][0] + bv[0]);
        float v1 = gelu_f(acc[mi][ni][1] + bv[1]);
        float v2 = gelu_f(acc[mi][ni][2] + bv[2]);
        float v3 = gelu_f(acc[mi][ni][3] + bv[3]);
        ss += (v0+v1)+(v2+v3);
        sq += (v0*v0+v1*v1)+(v2*v2+v3*v3);
        u32 w0 = pkbf(v0, v1), w1 = pkbf(v2, v3);
        u32 byte = (u32)(rl*256 + cl*2) ^ ((u32)(rl&7)<<4);
        *(u32*)(Cs + (byte>>1))     = w0;
        *(u32*)(Cs + (byte>>1) + 2) = w1;
      }
      ss += __shfl_xor(ss, 16, 64); ss += __shfl_xor(ss, 32, 64);
      sq += __shfl_xor(sq, 16, 64); sq += __shfl_xor(sq, 32, 64);
      if (g==0){
        int grow = m0 + rl;
        atomicAdd(&st2[2*grow],   ss);
        atomicAdd(&st2[2*grow+1], sq);
      }
    }
    __syncthreads();
    #pragma unroll
    for (int i=0;i<8;i++){
      int c = tid + i*512;
      int rl = c>>4, c0 = (c&15)*8;
      u32 byte = (u32)(rl*256 + c0*2) ^ ((u32)(rl&7)<<4);
      us8 v = *(const us8*)(Cs + (byte>>1));
      int row = m0 + rl, col = n0 + c0;
      *(us8*)((u16*)outv + (size_t)row*1024 + col) = v;
    }
  } else {
    #pragma unroll
    for (int mi=0;mi<4;mi++){
      int rl = wr*64 + mi*16 + lc16;
      int grow = m0 + rl;
      float s = stats[2*grow], q = stats[2*grow+1];
      float mean = s*(1.f/1024.f);
      float var  = q*(1.f/1024.f) - mean*mean;
      float rs = rsqrtf(var + 1e-5f);
      float mr = mean*rs;
      float mean2 = st2[2*grow];
      float istd2 = __builtin_amdgcn_rcpf(st2[2*grow+1]);
      size_t rowbase = (size_t)grow*256;
      #pragma unroll
      for (int ni=0;ni<4;ni++){
        int col = n0 + wc*64 + ni*16 + g*4;
        f4 bv = *(const f4*)(biasf + col);
        f4 cw = *(const f4*)(colsum + col);
        f4 v;
        #pragma unroll
        for (int j=0;j<4;j++) v[j] = acc[mi][ni][j]*rs - mr*cw[j] + bv[j];
        us4 xr = *(const us4*)(residb + rowbase + col);
        #pragma unroll
        for (int j=0;j<4;j++) v[j] += bf2f(xr[j])*istd2 + mean2;
        *(f4*)((float*)outv + rowbase + col) = v;
      }
    }
  }
}

__global__ __launch_bounds__(128)
void attn_mfma_kernel(
    const u16* __restrict__ qkv,
    const u16* __restrict__ cmb,
    u16* __restrict__ outb)
{
  __shared__ u16 smem2[2][12288];
  int wave = threadIdx.x>>6, lane = threadIdx.x&63;
  int pairbase = blockIdx.x*4 + wave*2;
  int bw = pairbase>>3, h0 = pairbase&7, w = bw&63;
  int lc = lane&15, g = lane>>4;
  u16* S = &smem2[wave][0];
  const u16* qg0 = qkv + (size_t)pairbase*(WA*32);
  const u16* qg1 = qg0 + WA*32;
  const u16* kg0 = qg0 + (size_t)NPAIR*(WA*32);
  const u16* kg1 = kg0 + WA*32;
  const u16* vg0 = qg0 + (size_t)2*NPAIR*(WA*32);
  const u16* vg1 = vg0 + WA*32;

  #pragma unroll
  for (int i=0;i<4;i++){
    int idx = i*64 + lane;
    if (idx < 196){
      glds16(kg0 + idx*8, S + idx*8);
      glds16(kg1 + idx*8, S + 2048 + idx*8);
    }
  }
  us8 vv0[4], vv1[4];
  #pragma unroll
  for (int i=0;i<4;i++){
    int idx = i*64+lane; int r = idx>>2, seg = idx&3;
    if (r < WA){
      vv0[i] = *(const us8*)(vg0 + r*32 + seg*8);
      vv1[i] = *(const us8*)(vg1 + r*32 + seg*8);
    } else {
      #pragma unroll
      for (int e=0;e<8;e++){ vv0[i][e]=0; vv1[i][e]=0; }
    }
  }
  bf16x8 qa0[4], qa1[4];
  #pragma unroll
  for (int mi=0;mi<4;mi++){
    int r = mi*16 + lc;
    if (r < WA){
      qa0[mi] = *(const bf16x8*)(qg0 + r*32 + g*8);
      qa1[mi] = *(const bf16x8*)(qg1 + r*32 + g*8);
    } else {
      bf16x8 z;
      #pragma unroll
      for (int e=0;e<8;e++) z[e]=0;
      qa0[mi]=z; qa1[mi]=z;
    }
  }
  #pragma unroll
  for (int i=0;i<4;i++){
    int idx = i*64+lane; int r = idx>>2, seg = idx&3;
    #pragma unroll
    for (int e=0;e<8;e++){
      int d = seg*8 + e;
      u32 byte = ((u32)(d*128 + r*2)) ^ ((u32)(d&7)<<4);
      S[4096 + (byte>>1)] = vv0[i][e];
      S[6144 + (byte>>1)] = vv1[i][e];
    }
  }
  asm volatile("s_waitcnt vmcnt(0)" ::: "memory");
  __builtin_amdgcn_sched_barrier(0);

  u16* Pp = S + 8192;
  #pragma unroll
  for (int p=0; p<2; ++p){
    const u16* Kp = S + p*2048;
    const u16* Vp = S + 4096 + p*2048;
    const u16* cmbp = cmb + ((size_t)((w*8 + h0 + p)*49))*64;

    f32x4 acc[4][4];
    #pragma unroll
    for (int i=0;i<4;i++)
      #pragma unroll
      for (int j=0;j<4;j++){ acc[i][j][0]=0.f; acc[i][j][1]=0.f; acc[i][j][2]=0.f; acc[i][j][3]=0.f; }

    __builtin_amdgcn_s_setprio(1);
    #pragma unroll
    for (int ni=0;ni<4;ni++){
      bf16x8 kb = *(const bf16x8*)(Kp + (ni*16+lc)*32 + g*8);
      #pragma unroll
      for (int mi=0;mi<4;mi++)
        acc[mi][ni] = __builtin_amdgcn_mfma_f32_16x16x32_bf16(p==0 ? qa0[mi] : qa1[mi], kb, acc[mi][ni], 0, 0, 0);
    }
    __builtin_amdgcn_s_setprio(0);

    float rinv[4][4];
    #pragma unroll
    for (int mi=0;mi<4;mi++){
      #pragma unroll
      for (int jr=0;jr<4;jr++){
        int i = mi*16 + g*4 + jr;
        float sv[4];
        #pragma unroll
        for (int ni=0;ni<4;ni++){
          int j = ni*16 + lc;
          float s;
          if (i < WA && j < WA){
            s = acc[mi][ni][jr] + bf2f(cmbp[i*64 + j]);
          } else s = -1e9f;
          sv[ni] = s;
        }
        float mx = fmaxf(fmaxf(sv[0],sv[1]), fmaxf(sv[2],sv[3]));
        #pragma unroll
        for (int off=1; off<16; off<<=1) mx = fmaxf(mx, __shfl_xor(mx, off, 64));
        float sum = 0.f;
        #pragma unroll
        for (int ni=0;ni<4;ni++){ sv[ni] = __expf(sv[ni]-mx); sum += sv[ni]; }
        #pragma unroll
        for (int off=1; off<16; off<<=1) sum += __shfl_xor(sum, off, 64);
        rinv[mi][jr] = __builtin_amdgcn_rcpf(sum);
        #pragma unroll
        for (int ni=0;ni<4;ni++){
          int j = ni*16 + lc;
          u32 byte = ((u32)(i*128 + j*2)) ^ ((u32)(i&7)<<4);
          Pp[byte>>1] = f2bf(sv[ni]);
        }
      }
    }

    bf16x8 vb[2][2];
    #pragma unroll
    for (int kk=0;kk<2;kk++)
      #pragma unroll
      for (int ni=0;ni<2;ni++){
        int d = ni*16 + lc;
        u32 byte = ((u32)(d*128 + kk*64 + g*16)) ^ ((u32)(d&7)<<4);
        vb[kk][ni] = *(const bf16x8*)(Vp + (byte>>1));
      }
    f32x4 aco[4][2];
    #pragma unroll
    for (int i=0;i<4;i++)
      #pragma unroll
      for (int j=0;j<2;j++){ aco[i][j][0]=0.f; aco[i][j][1]=0.f; aco[i][j][2]=0.f; aco[i][j][3]=0.f; }
    __builtin_amdgcn_s_setprio(1);
    #pragma unroll
    for (int mi=0;mi<4;mi++){
      int r = mi*16 + lc;
      #pragma unroll
      for (int kk=0;kk<2;kk++){
        u32 byte = ((u32)(r*128 + kk*64 + g*16)) ^ ((u32)(r&7)<<4);
        bf16x8 pa = *(const bf16x8*)(Pp + (byte>>1));
        #pragma unroll
        for (int ni=0;ni<2;ni++)
          aco[mi][ni] = __builtin_amdgcn_mfma_f32_16x16x32_bf16(pa, vb[kk][ni], aco[mi][ni], 0, 0, 0);
      }
    }
    __builtin_amdgcn_s_setprio(0);

    u16* Op = S + p*2048;
    #pragma unroll
    for (int mi=0;mi<4;mi++){
      #pragma unroll
      for (int jr=0;jr<4;jr++){
        int i = mi*16 + g*4 + jr;
        if (i < WA){
          float rv = rinv[mi][jr];
          #pragma unroll
          for (int ni=0;ni<2;ni++)
            Op[i*32 + ni*16 + lc] = f2bf(aco[mi][ni][jr]*rv);
        }
      }
    }
    size_t obase = (size_t)(bw*WA)*256 + (h0+p)*32;
    #pragma unroll
    for (int i=0;i<4;i++){
      int c = i*64 + lane;
      if (c < WA*4){
        int t = c>>2, seg = c&3;
        *(us8*)(outb + obase + (size_t)t*256 + seg*8) = *(const us8*)(Op + t*32 + seg*8);
      }
    }
  }
}

extern "C" void kernel_launch(void* const* d_in, const int* in_sizes, int n_in,
                              void* d_out, int out_size, void* d_ws, size_t ws_size,
                              hipStream_t stream) {
  const float* x      = (const float*)d_in[0];
  const float* ln1w   = (const float*)d_in[1];
  const float* ln1b   = (const float*)d_in[2];
  const float* qkv_w  = (const float*)d_in[3];
  const float* qkv_b  = (const float*)d_in[4];
  const float* rpb    = (const float*)d_in[5];
  const float* proj_w = (const float*)d_in[6];
  const float* proj_b = (const float*)d_in[7];
  const float* ln2w   = (const float*)d_in[8];
  const float* ln2b   = (const float*)d_in[9];
  const float* fc1_w  = (const float*)d_in[10];
  const float* fc1_b  = (const float*)d_in[11];
  const float* ln3w   = (const float*)d_in[12];
  const float* ln3b   = (const float*)d_in[13];
  const float* fc2_w  = (const float*)d_in[14];
  const float* fc2_b  = (const float*)d_in[15];
  const float* amask  = (const float*)d_in[16];
  const int*   rel    = (const int*)d_in[17];
  float* out = (float*)d_out;

  char* ws = (char*)d_ws;
  float* hstats = (float*)(ws);
  float* stats2 = (float*)(ws +  802816);
  float* bq     = (float*)(ws + 1605632);
  float* b1     = (float*)(ws + 1608704);
  float* b2     = (float*)(ws + 1612800);
  float* bp     = (float*)(ws + 1613824);
  float* cs2    = (float*)(ws + 1614848);
  u16*   wq     = (u16*)  (ws + 1615872);
  u16*   w1     = (u16*)  (ws + 2009088);
  u16*   w2     = (u16*)  (ws + 2533376);
  u16*   wp     = (u16*)  (ws + 3057664);
  const size_t P0 = 3188736;
  u16*   qkvbuf = (u16*)(ws + P0);
  u16*   attno  = (u16*)(ws + P0 + 154140672);
  u16*   xb     = (u16*)(ws + P0 + 154140672);
  u16*   ob     = (u16*)(ws + P0);
  u16*   hbuf   = (u16*)(ws + P0);
  u16*   x1b    = (u16*)(ws + P0 + 205520896);
  u16*   cmb    = (u16*)(ws + P0 + 205520896);
  const int bigws = (ws_size >= (size_t)(P0 + 205520896ull + 51380224ull));

  prep_weights<<<576,256,0,stream>>>(qkv_w,qkv_b,ln1w,ln1b, fc1_w,fc1_b,ln2w,ln2b,
                                     fc2_w,fc2_b,ln3w,ln3b, proj_w,proj_b,
                                     wq,bq, w1,b1, w2,b2, wp,bp, cs2, hstats);
  cmb_kernel<<<1568,256,0,stream>>>(rpb, rel, amask, cmb);
  ln_apply_kernel<<<NTOK/4,256,0,stream>>>(x, xb);
  gemm18<0,0,0,2><<<784*6,256,0,stream>>>(xb, wq, nullptr, nullptr, bq, nullptr, nullptr, qkvbuf, 256, 6, 588);
  attn_mfma_kernel<<<NPAIR/4,128,0,stream>>>(qkvbuf, cmb, attno);
  if (bigws){
    gemm18<1,5,1,2><<<784*2,256,0,stream>>>(attno, wp, nullptr, nullptr, bp, x, nullptr, ob, 256, 2, 196);
    ln_apply_b_kernel<<<NTOK/4,256,0,stream>>>(ob, x1b, stats2);
    gemm19<2><<<3136,512,0,stream>>>(x1b, w1, nullptr, hstats, b1, nullptr, nullptr, hbuf, 256, 8, 392);
    gemm19<6><<<784,512,0,stream>>>(hbuf, w2, hstats, stats2, b2, x1b, cs2, out, 1024, 2, 98);
  } else {
    gemm18<1,1,1,2><<<784*2,256,0,stream>>>(attno, wp, nullptr, nullptr, bp, x, nullptr, out, 256, 2, 196);
    ln_stats_kernel<256,0><<<NTOK/4,256,0,stream>>>(out, stats2);
    gemm18<3,2,1,2><<<784*8,256,0,stream>>>(out, w1, stats2, hstats, b1, nullptr, nullptr, (u16*)(ws+P0), 256, 8, 784);
    gemm18<1,4,1,2><<<784*2,256,0,stream>>>((u16*)(ws+P0), w2, hstats, nullptr, b2, out, cs2, out, 1024, 2, 196);
  }
}

// Round 29
// 525.054 us; speedup vs baseline: 1.0181x; 1.0181x over previous
//
#include <hip/hip_runtime.h>
#include <hip/hip_bf16.h>
#include <math.h>

typedef __attribute__((ext_vector_type(8))) short bf16x8;
typedef __attribute__((ext_vector_type(4))) float f32x4;
typedef __attribute__((ext_vector_type(4))) float f4;
typedef __attribute__((ext_vector_type(8))) unsigned short us8;
typedef __attribute__((ext_vector_type(4))) unsigned short us4;
typedef unsigned short u16;
typedef unsigned int u32;

#define HEADS 8
#define SHIFT_ 3
#define HIMG 56
#define WIMG 56
#define WA 49
#define NTOK 100352
#define NPAIR 16384

static __device__ __forceinline__ float bf2f(u16 v){ return __uint_as_float(((u32)v)<<16); }
static __device__ __forceinline__ u16 f2bf(float f){
  u32 u = __float_as_uint(f);
  return (u16)((u + 0x7fffu + ((u>>16)&1u)) >> 16);
}
static __device__ __forceinline__ u32 pkbf(float a, float b){
  __hip_bfloat162 h = __float22bfloat162_rn(make_float2(a, b));
  return *reinterpret_cast<u32*>(&h);
}
static __device__ __forceinline__ float wsum(float v){
  #pragma unroll
  for (int off=32; off>0; off>>=1) v += __shfl_xor(v, off, 64);
  return v;
}
static __device__ __forceinline__ void glds16(const u16* g, u16* l){
  __builtin_amdgcn_global_load_lds(
      (const __attribute__((address_space(1))) unsigned int*)g,
      (__attribute__((address_space(3))) unsigned int*)l, 16, 0, 0);
}
static __device__ __forceinline__ int tok2pix(int row){
  int bw = row / 49, t = row - bw*49;
  int b  = bw >> 6,  w = bw & 63;
  int wh = w >> 3,   ww = w & 7;
  int th = t / 7,    tw = t - th*7;
  int r = wh*7 + th + SHIFT_; if (r >= HIMG) r -= HIMG;
  int c = ww*7 + tw + SHIFT_; if (c >= WIMG) c -= WIMG;
  return (b*HIMG + r)*WIMG + c;
}
static __device__ __forceinline__ float gelu_f(float x){
  float e = __expf(-1.702f*x);
  return x*__builtin_amdgcn_rcpf(1.0f+e);
}

template<int C, int ISBF>
__global__ void ln_stats_kernel(const void* __restrict__ srcv, float* __restrict__ stats){
  int wave = threadIdx.x >> 6, lane = threadIdx.x & 63;
  int tok = blockIdx.x*4 + wave;
  float s=0.f, s2=0.f;
  if (ISBF == 0){
    const float* p = (const float*)srcv + (size_t)tok*C;
    #pragma unroll
    for (int i=0;i<C/256;i++){
      f4 v = *(const f4*)(p + lane*4*(C/256) + i*4);
      #pragma unroll
      for (int e=0;e<4;e++){ float f=v[e]; s+=f; s2+=f*f; }
    }
  } else {
    const u16* p = (const u16*)srcv + (size_t)tok*C;
    #pragma unroll
    for (int i=0;i<C/512;i++){
      us8 v = *(const us8*)(p + lane*8*(C/512) + i*8);
      #pragma unroll
      for (int e=0;e<8;e++){ float f=bf2f(v[e]); s+=f; s2+=f*f; }
    }
  }
  s = wsum(s); s2 = wsum(s2);
  if (lane==0){
    float mean = s/(float)C;
    float var  = s2/(float)C - mean*mean;
    stats[2*tok]   = mean;
    stats[2*tok+1] = rsqrtf(var + 1e-5f);
  }
}

__global__ void ln_apply_kernel(const float* __restrict__ src, u16* __restrict__ dst){
  int wave = threadIdx.x >> 6, lane = threadIdx.x & 63;
  int tok = blockIdx.x*4 + wave;
  const float* p = src + (size_t)tok*256;
  f4 a = *(const f4*)(p + lane*4);
  float s = a[0]+a[1]+a[2]+a[3];
  float s2 = a[0]*a[0]+a[1]*a[1]+a[2]*a[2]+a[3]*a[3];
  s = wsum(s); s2 = wsum(s2);
  float mean = s*(1.f/256.f);
  float var  = s2*(1.f/256.f) - mean*mean;
  float rstd = rsqrtf(var + 1e-5f);
  u32 o2[2];
  o2[0] = pkbf((a[0]-mean)*rstd, (a[1]-mean)*rstd);
  o2[1] = pkbf((a[2]-mean)*rstd, (a[3]-mean)*rstd);
  *(u32*)(dst + (size_t)tok*256 + lane*4)     = o2[0];
  *(u32*)(dst + (size_t)tok*256 + lane*4 + 2) = o2[1];
}

__global__ void ln_apply_b_kernel(const u16* __restrict__ src, u16* __restrict__ dst,
                                  float* __restrict__ st){
  int wave = threadIdx.x >> 6, lane = threadIdx.x & 63;
  int tok = blockIdx.x*4 + wave;
  const u16* p = src + (size_t)tok*256 + lane*4;
  us4 a4 = *(const us4*)p;
  float a0=bf2f(a4[0]), a1=bf2f(a4[1]), a2=bf2f(a4[2]), a3=bf2f(a4[3]);
  float s = a0+a1+a2+a3;
  float s2 = a0*a0+a1*a1+a2*a2+a3*a3;
  s = wsum(s); s2 = wsum(s2);
  float mean = s*(1.f/256.f);
  float var  = s2*(1.f/256.f) - mean*mean;
  float rstd = rsqrtf(var + 1e-5f);
  u32 o0 = pkbf((a0-mean)*rstd, (a1-mean)*rstd);
  u32 o1 = pkbf((a2-mean)*rstd, (a3-mean)*rstd);
  u16* d = dst + (size_t)tok*256 + lane*4;
  *(u32*)d     = o0;
  *(u32*)(d+2) = o1;
  if (lane==0){ st[2*tok] = mean; st[2*tok+1] = rstd; }
}

__global__ void cmb_kernel(const float* __restrict__ rpb, const int* __restrict__ rel,
                           const float* __restrict__ mask, u16* __restrict__ cmb){
  int lin = blockIdx.x*1024 + threadIdx.x*4;
  int j0 = lin & 63;
  int r3 = lin >> 6;
  int i  = r3 % 49;
  int wh = r3 / 49;
  int h = wh & 7, w = wh >> 3;
  us4 o;
  #pragma unroll
  for (int e=0;e<4;e++){
    int j = j0 + e;
    float v = 0.f;
    if (j < WA) v = rpb[rel[i*WA+j]*8 + h] + mask[((size_t)w*WA + i)*WA + j];
    o[e] = f2bf(v);
  }
  *(us4*)(cmb + lin) = o;
}

__global__ void prep_weights(
    const float* __restrict__ qkv_w, const float* __restrict__ qkv_b,
    const float* __restrict__ ln1w,  const float* __restrict__ ln1b,
    const float* __restrict__ fc1_w, const float* __restrict__ fc1_b,
    const float* __restrict__ ln2w,  const float* __restrict__ ln2b,
    const float* __restrict__ fc2_w, const float* __restrict__ fc2_b,
    const float* __restrict__ ln3w,  const float* __restrict__ ln3b,
    const float* __restrict__ proj_w, const float* __restrict__ proj_b,
    u16* __restrict__ wq, float* __restrict__ bq,
    u16* __restrict__ w1, float* __restrict__ b1,
    u16* __restrict__ w2, float* __restrict__ b2,
    u16* __restrict__ wp, float* __restrict__ bp,
    float* __restrict__ cs2, float* __restrict__ hstats)
{
  for (int idx = blockIdx.x*256 + threadIdx.x; idx < 2*NTOK; idx += gridDim.x*256)
    hstats[idx] = 0.f;

  int wave = threadIdx.x>>6, lane = threadIdx.x&63;
  int n = blockIdx.x*4 + wave;
  const float *W,*lw,*lb,*bs; u16* WO; float* BO; int K, row, noln, docs;
  float qs = 1.f;
  if (n < 768)      { W=qkv_w; lw=ln1w; lb=ln1b; bs=qkv_b; WO=wq; BO=bq; K=256;  row=n;      noln=0; docs=0;
                      if (n < 256) qs = 0.17677669529663689f; }
  else if (n < 1792){ W=fc1_w; lw=ln2w; lb=ln2b; bs=fc1_b; WO=w1; BO=b1; K=256;  row=n-768;  noln=0; docs=0; }
  else if (n < 2048){ W=fc2_w; lw=ln3w; lb=ln3b; bs=fc2_b; WO=w2; BO=b2; K=1024; row=n-1792; noln=0; docs=1; }
  else              { W=proj_w; lw=nullptr; lb=nullptr; bs=proj_b; WO=wp; BO=bp; K=256; row=n-2048; noln=1; docs=0; }
  float dot = 0.f, cs = 0.f;
  for (int k=lane; k<K; k+=64){
    float wv = W[(size_t)row*K + k];
    if (noln){
      WO[(size_t)row*K + k] = f2bf(wv);
    } else {
      dot += wv * lb[k];
      u16 q = f2bf(wv * lw[k] * qs);
      WO[(size_t)row*K + k] = q;
      cs += bf2f(q);
    }
  }
  dot = wsum(dot);
  if (docs){ cs = wsum(cs); if (lane==0) cs2[row] = cs; }
  if (lane==0) BO[row] = (bs[row] + dot) * qs;
}

// GEMM v18 (R27-proven): BM=128, (DEPTH+1)-buffer depth-DEPTH prefetch, counted vmcnt
template<int SMODE, int EPI, int SWAP, int DEPTH>
__global__ __launch_bounds__(256)
void gemm18(const void* __restrict__ Av, const u16* __restrict__ Bt,
            const float* __restrict__ stats, float* __restrict__ hstats,
            const float* __restrict__ biasf, const float* __restrict__ resid,
            const float* __restrict__ colsum, void* __restrict__ outv,
            int K, int NT, int CHUNK)
{
  constexpr int BM=128, BN=128, BK=32;
  constexpr int NBUF = DEPTH + 1;
  __shared__ u16 smem[NBUF*8192];
  constexpr int BOFF = NBUF*4096;
  int b = blockIdx.x;
  int linear = (b & 7)*CHUNK + (b >> 3);
  int mt = linear / NT, nt = linear - mt*NT;
  int m0 = mt*BM, n0 = nt*BN;
  int tid  = threadIdx.x;
  int lane = tid & 63, wave = tid >> 6;
  int wr = wave >> 1, wc = wave & 1;
  int lc16 = lane & 15, g = lane >> 4;
  int nsteps = K >> 5;

  const u16* asrc[2];
  const u16* bsrc[2];
  #pragma unroll
  for (int i=0;i<2;i++){
    int c = tid + i*256;
    int row = c >> 2, gch = ((c & 3) - (row >> 1)) & 3;
    if (SMODE <= 1){
      int grow = (SMODE==0) ? tok2pix(m0+row) : (m0+row);
      asrc[i] = (const u16*)Av + (size_t)grow*K + gch*8;
    }
    bsrc[i] = Bt + (size_t)(n0+row)*K + gch*8;
  }
  float smean[2], srstd[2];
  if (SMODE == 3){
    #pragma unroll
    for (int i=0;i<2;i++){
      int grow = m0 + ((tid + i*256) >> 2);
      smean[i] = stats[2*grow]; srstd[i] = stats[2*grow+1];
    }
  }

  f32x4 acc[4][4];
  #pragma unroll
  for (int i=0;i<4;i++)
    #pragma unroll
    for (int j=0;j<4;j++){ acc[i][j][0]=0.f; acc[i][j][1]=0.f; acc[i][j][2]=0.f; acc[i][j][3]=0.f; }

  if (SMODE <= 1){
    #pragma unroll
    for (int pt=0; pt<DEPTH; ++pt){
      int kt = pt << 5;
      #pragma unroll
      for (int i=0;i<2;i++) glds16(asrc[i]+kt, smem + pt*4096 + i*2048 + wave*512);
      #pragma unroll
      for (int i=0;i<2;i++) glds16(bsrc[i]+kt, smem + BOFF + pt*4096 + i*2048 + wave*512);
    }
    asm volatile("s_waitcnt vmcnt(4)" ::: "memory");
    __builtin_amdgcn_s_barrier();

    int cur = 0;
    for (int t=0; t<nsteps; ++t){
      if (t+DEPTH < nsteps){
        int ktD = (t+DEPTH) << 5;
        int nb = cur + DEPTH; if (nb >= NBUF) nb -= NBUF;
        int off = nb*4096;
        #pragma unroll
        for (int i=0;i<2;i++) glds16(asrc[i]+ktD, smem + off + i*2048 + wave*512);
        #pragma unroll
        for (int i=0;i<2;i++) glds16(bsrc[i]+ktD, smem + BOFF + off + i*2048 + wave*512);
      }
      const u16* Ap = smem + cur*4096;
      const u16* Bp = smem + BOFF + cur*4096;
      bf16x8 af[4], bfr[4];
      #pragma unroll
      for (int mi=0;mi<4;mi++){
        int r = wr*64 + mi*16 + lc16;
        u32 byte = (u32)(r*64) + ((u32)((g + (r>>1)) & 3) << 4);
        af[mi] = *(const bf16x8*)(Ap + (byte>>1));
      }
      #pragma unroll
      for (int ni=0;ni<4;ni++){
        int r = wc*64 + ni*16 + lc16;
        u32 byte = (u32)(r*64) + ((u32)((g + (r>>1)) & 3) << 4);
        bfr[ni] = *(const bf16x8*)(Bp + (byte>>1));
      }
      #pragma unroll
      for (int mi=0;mi<4;mi++)
        #pragma unroll
        for (int ni=0;ni<4;ni++)
          acc[mi][ni] = SWAP ? __builtin_amdgcn_mfma_f32_16x16x32_bf16(bfr[ni], af[mi], acc[mi][ni], 0, 0, 0)
                             : __builtin_amdgcn_mfma_f32_16x16x32_bf16(af[mi], bfr[ni], acc[mi][ni], 0, 0, 0);
      int rem = nsteps - 1 - t;
      int cnt = (rem < DEPTH) ? rem : DEPTH;
      if (cnt >= 2)      asm volatile("s_waitcnt vmcnt(4)" ::: "memory");
      else if (cnt == 1) asm volatile("s_waitcnt vmcnt(0)" ::: "memory");
      __builtin_amdgcn_s_barrier();
      cur = (cur+1 == NBUF) ? 0 : cur+1;
    }
  } else {
    f4 rcurf[2][2];
    #pragma unroll
    for (int i=0;i<2;i++){
      int c = tid + i*256; int row = c>>2, gch = ((c&3) - (row>>1)) & 3;
      const float* ap = (const float*)Av + (size_t)(m0+row)*K + gch*8;
      rcurf[i][0] = *(const f4*)ap; rcurf[i][1] = *(const f4*)(ap+4);
    }
    for (int t=0; t<nsteps; ++t){
      int kt = t << 5;
      #pragma unroll
      for (int i=0;i<2;i++){
        int c = tid + i*256; int row = c>>2, s = c&3;
        us8 o;
        #pragma unroll
        for (int e=0;e<8;e++){
          float fv = rcurf[i][e>>2][e&3];
          o[e] = f2bf((fv - smean[i])*srstd[i]);
        }
        u32 byte = (u32)(row*64) + ((u32)s << 4);
        *(us8*)(smem + (byte>>1)) = o;
      }
      #pragma unroll
      for (int i=0;i<2;i++) glds16(bsrc[i]+kt, smem + BOFF + i*2048 + wave*512);
      __syncthreads();
      if (t+1 < nsteps){
        int kt1 = kt + 32;
        #pragma unroll
        for (int i=0;i<2;i++){
          int c = tid + i*256; int row = c>>2, gch = ((c&3) - (row>>1)) & 3;
          const float* ap = (const float*)Av + (size_t)(m0+row)*K + kt1 + gch*8;
          rcurf[i][0] = *(const f4*)ap; rcurf[i][1] = *(const f4*)(ap+4);
        }
      }
      bf16x8 af[4], bfr[4];
      #pragma unroll
      for (int mi=0;mi<4;mi++){
        int r = wr*64 + mi*16 + lc16;
        u32 byte = (u32)(r*64) + ((u32)((g + (r>>1)) & 3) << 4);
        af[mi] = *(const bf16x8*)(smem + (byte>>1));
      }
      #pragma unroll
      for (int ni=0;ni<4;ni++){
        int r = wc*64 + ni*16 + lc16;
        u32 byte = (u32)(r*64) + ((u32)((g + (r>>1)) & 3) << 4);
        bfr[ni] = *(const bf16x8*)(smem + BOFF + (byte>>1));
      }
      #pragma unroll
      for (int mi=0;mi<4;mi++)
        #pragma unroll
        for (int ni=0;ni<4;ni++)
          acc[mi][ni] = SWAP ? __builtin_amdgcn_mfma_f32_16x16x32_bf16(bfr[ni], af[mi], acc[mi][ni], 0, 0, 0)
                             : __builtin_amdgcn_mfma_f32_16x16x32_bf16(af[mi], bfr[ni], acc[mi][ni], 0, 0, 0);
      __syncthreads();
    }
  }

  int lr = lane >> 4;
  if (EPI==0){
    u16* Cs = smem;
    #pragma unroll
    for (int mi=0;mi<4;mi++){
      #pragma unroll
      for (int ni=0;ni<4;ni++){
        int cl = wc*64 + ni*16 + lc16;
        float bv = biasf[n0 + cl];
        #pragma unroll
        for (int j=0;j<4;j++){
          int rl = wr*64 + mi*16 + lr*4 + j;
          float v = acc[mi][ni][j] + bv;
          u32 byte = (u32)(rl*256 + cl*2) ^ ((u32)(rl&7)<<4);
          Cs[byte>>1] = f2bf(v);
        }
      }
    }
    __syncthreads();
    #pragma unroll
    for (int i=0;i<8;i++){
      int c = tid + i*256;
      int rl = c>>4, c0 = (c&15)*8;
      u32 byte = (u32)(rl*256 + c0*2) ^ ((u32)(rl&7)<<4);
      us8 v = *(const us8*)(Cs + (byte>>1));
      int row = m0 + rl, col = n0 + c0;
      int which = col>>8, hh = (col>>5)&7, d0 = col&31;
      int bwi = row/49, t = row - bwi*49;
      *(us8*)((u16*)outv + ((size_t)which*NPAIR + bwi*8 + hh)*(WA*32) + t*32 + d0) = v;
    }
  } else if (EPI==5){
    u16* Cs = smem;
    #pragma unroll
    for (int mi=0;mi<4;mi++){
      int rl = wr*64 + mi*16 + lc16;
      int pix = tok2pix(m0 + rl);
      #pragma unroll
      for (int ni=0;ni<4;ni++){
        int cl = wc*64 + ni*16 + g*4;
        int col = n0 + cl;
        f4 bv = *(const f4*)(biasf + col);
        f4 rr = *(const f4*)(resid + (size_t)pix*256 + col);
        float v0 = acc[mi][ni][0] + bv[0] + rr[0];
        float v1 = acc[mi][ni][1] + bv[1] + rr[1];
        float v2 = acc[mi][ni][2] + bv[2] + rr[2];
        float v3 = acc[mi][ni][3] + bv[3] + rr[3];
        u32 w0 = pkbf(v0, v1), w1 = pkbf(v2, v3);
        u32 byte = (u32)(rl*256 + cl*2) ^ ((u32)(rl&7)<<4);
        *(u32*)(Cs + (byte>>1))     = w0;
        *(u32*)(Cs + (byte>>1) + 2) = w1;
      }
    }
    __syncthreads();
    #pragma unroll
    for (int i=0;i<8;i++){
      int c = tid + i*256;
      int rl = c>>4, c0 = (c&15)*8;
      u32 byte = (u32)(rl*256 + c0*2) ^ ((u32)(rl&7)<<4);
      us8 v = *(const us8*)(Cs + (byte>>1));
      int pix = tok2pix(m0 + rl);
      *(us8*)((u16*)outv + (size_t)pix*256 + n0 + c0) = v;
    }
  } else if (EPI==2){
    u16* Cs = smem;
    #pragma unroll
    for (int mi=0;mi<4;mi++){
      int rl = wr*64 + mi*16 + lc16;
      float ss = 0.f, sq = 0.f;
      #pragma unroll
      for (int ni=0;ni<4;ni++){
        int cl = wc*64 + ni*16 + g*4;
        f4 bv = *(const f4*)(biasf + n0 + cl);
        float v0 = gelu_f(acc[mi][ni][0] + bv[0]);
        float v1 = gelu_f(acc[mi][ni][1] + bv[1]);
        float v2 = gelu_f(acc[mi][ni][2] + bv[2]);
        float v3 = gelu_f(acc[mi][ni][3] + bv[3]);
        ss += (v0+v1)+(v2+v3);
        sq += (v0*v0+v1*v1)+(v2*v2+v3*v3);
        u32 w0 = pkbf(v0, v1), w1 = pkbf(v2, v3);
        u32 byte = (u32)(rl*256 + cl*2) ^ ((u32)(rl&7)<<4);
        *(u32*)(Cs + (byte>>1))     = w0;
        *(u32*)(Cs + (byte>>1) + 2) = w1;
      }
      ss += __shfl_xor(ss, 16, 64); ss += __shfl_xor(ss, 32, 64);
      sq += __shfl_xor(sq, 16, 64); sq += __shfl_xor(sq, 32, 64);
      if (g==0){
        int grow = m0 + rl;
        atomicAdd(&hstats[2*grow],   ss);
        atomicAdd(&hstats[2*grow+1], sq);
      }
    }
    __syncthreads();
    #pragma unroll
    for (int i=0;i<8;i++){
      int c = tid + i*256;
      int rl = c>>4, c0 = (c&15)*8;
      u32 byte = (u32)(rl*256 + c0*2) ^ ((u32)(rl&7)<<4);
      us8 v = *(const us8*)(Cs + (byte>>1));
      int row = m0 + rl, col = n0 + c0;
      *(us8*)((u16*)outv + (size_t)row*1024 + col) = v;
    }
  } else {
    #pragma unroll
    for (int mi=0;mi<4;mi++){
      int rl = wr*64 + mi*16 + lc16;
      int grow = m0 + rl;
      float rs = 1.f, mr = 0.f, istd2 = 0.f, mean2 = 0.f;
      if (EPI==4 || EPI==6){
        float s = stats[2*grow], q = stats[2*grow+1];
        float mean = s*(1.f/1024.f);
        float var  = q*(1.f/1024.f) - mean*mean;
        rs = rsqrtf(var + 1e-5f);
        mr = mean*rs;
      }
      if (EPI==6){
        mean2 = hstats[2*grow];
        istd2 = __builtin_amdgcn_rcpf(hstats[2*grow+1]);
      }
      size_t rowbase = (EPI==1) ? (size_t)tok2pix(grow)*256 : (size_t)grow*256;
      #pragma unroll
      for (int ni=0;ni<4;ni++){
        int col = n0 + wc*64 + ni*16 + g*4;
        f4 bv = *(const f4*)(biasf + col);
        f4 v;
        if (EPI==4 || EPI==6){
          f4 cw = *(const f4*)(colsum + col);
          #pragma unroll
          for (int j=0;j<4;j++) v[j] = acc[mi][ni][j]*rs - mr*cw[j] + bv[j];
        } else {
          #pragma unroll
          for (int j=0;j<4;j++) v[j] = acc[mi][ni][j] + bv[j];
        }
        if (EPI==6){
          us4 xr = *(const us4*)((const u16*)resid + rowbase + col);
          #pragma unroll
          for (int j=0;j<4;j++) v[j] += bf2f(xr[j])*istd2 + mean2;
        } else {
          f4 rr = *(const f4*)(resid + rowbase + col);
          v += rr;
        }
        *(f4*)((float*)outv + rowbase + col) = v;
      }
    }
  }
}

// ---------------- fused MLP: x1b -> fc1+GELU -> LN3(in-block) -> fc2 -> +resid -> out ----------------
// Block = 128 rows x full 1024 hidden. 512 thr (8 waves: wr=wave>>2, wcol=wave&3).
// LDS 128 KB: A[0,32768) rot32 | H[32768,49152) rot16 | dbuf[49152,65536) 2x8192 u16.
__global__ __launch_bounds__(512)
void mlp_fused(const u16* __restrict__ x1b, const u16* __restrict__ w1,
               const u16* __restrict__ w2, const float* __restrict__ b1,
               const float* __restrict__ b2, const float* __restrict__ colsum,
               const float* __restrict__ st2, float* __restrict__ outv)
{
  __shared__ u16 smem[65536];
  u16* Al = smem;
  u16* Hl = smem + 32768;
  u16* Db = smem + 49152;

  int b = blockIdx.x;
  int linear = (b & 7)*98 + (b >> 3);
  int m0 = linear * 128;
  int tid = threadIdx.x;
  int lane = tid & 63, wave = tid >> 6;
  int wr = wave >> 2, wcol = wave & 3;
  int lc16 = lane & 15, g = lane >> 4;

  // prologue: A (128x256, rot32) + B1[n=0,t=0] -> slot0
  #pragma unroll
  for (int i=0;i<8;i++){
    int c = tid + i*512;
    int row = c >> 5, s = c & 31, gs = (s - row) & 31;
    glds16(x1b + (size_t)(m0+row)*256 + gs*8, Al + i*4096 + wave*512);
  }
  #pragma unroll
  for (int i=0;i<2;i++){
    int c = tid + i*512;
    int hrow = c >> 3, s = c & 7, gs = (s - hrow) & 7;
    glds16(w1 + (size_t)hrow*256 + gs*8, Db + i*4096 + wave*512);
  }
  asm volatile("s_waitcnt vmcnt(0)" ::: "memory");
  __builtin_amdgcn_s_barrier();

  f32x4 acc2[4][4];
  #pragma unroll
  for (int i=0;i<4;i++)
    #pragma unroll
    for (int j=0;j<4;j++){ acc2[i][j][0]=0.f; acc2[i][j][1]=0.f; acc2[i][j][2]=0.f; acc2[i][j][3]=0.f; }
  float ss[4] = {0.f,0.f,0.f,0.f};
  float sq[4] = {0.f,0.f,0.f,0.f};

  #pragma unroll 1
  for (int n=0; n<8; ++n){
    f32x4 acc1[4][2];
    #pragma unroll
    for (int i=0;i<4;i++)
      #pragma unroll
      for (int j=0;j<2;j++){ acc1[i][j][0]=0.f; acc1[i][j][1]=0.f; acc1[i][j][2]=0.f; acc1[i][j][3]=0.f; }

    // ---- fc1: 4 steps of BK=64 over K=256 ----
    #pragma unroll
    for (int t=0; t<4; ++t){
      if (t < 3){
        #pragma unroll
        for (int i=0;i<2;i++){
          int c = tid + i*512;
          int hrow = c >> 3, s = c & 7, gs = (s - hrow) & 7;
          glds16(w1 + (size_t)(n*128+hrow)*256 + (t+1)*64 + gs*8,
                 Db + ((t+1)&1)*8192 + i*4096 + wave*512);
        }
      } else {
        #pragma unroll
        for (int i=0;i<2;i++){
          int c = tid + i*512;
          int crow = c >> 2, s = c & 3, gs = (s - crow) & 3;
          glds16(w2 + (size_t)crow*1024 + n*128 + gs*8,
                 Db + i*4096 + wave*512);               // slot0
        }
      }
      const u16* Bp = Db + (t&1)*8192;
      #pragma unroll
      for (int kk=0; kk<2; ++kk){
        bf16x8 af[4], bff[2];
        #pragma unroll
        for (int mi=0;mi<4;mi++){
          int r = wr*64 + mi*16 + lc16;
          int gsA = t*8 + kk*4 + g;
          af[mi] = *(const bf16x8*)(Al + r*256 + ((gsA + r)&31)*8);
        }
        #pragma unroll
        for (int ni=0;ni<2;ni++){
          int hr = wcol*32 + ni*16 + lc16;
          bff[ni] = *(const bf16x8*)(Bp + hr*64 + (((kk*4+g) + hr)&7)*8);
        }
        #pragma unroll
        for (int mi=0;mi<4;mi++)
          #pragma unroll
          for (int ni=0;ni<2;ni++)
            acc1[mi][ni] = __builtin_amdgcn_mfma_f32_16x16x32_bf16(bff[ni], af[mi], acc1[mi][ni], 0, 0, 0);
      }
      if (t < 3){
        asm volatile("s_waitcnt vmcnt(0)" ::: "memory");
        __builtin_amdgcn_s_barrier();
      } else {
        // GELU + bias, stats accumulate, write h to LDS (rot16)
        #pragma unroll
        for (int mi=0;mi<4;mi++){
          int r = wr*64 + mi*16 + lc16;
          #pragma unroll
          for (int ni=0;ni<2;ni++){
            int colh = wcol*32 + ni*16 + g*4;
            f4 bv = *(const f4*)(b1 + n*128 + colh);
            float v0 = gelu_f(acc1[mi][ni][0] + bv[0]);
            float v1 = gelu_f(acc1[mi][ni][1] + bv[1]);
            float v2 = gelu_f(acc1[mi][ni][2] + bv[2]);
            float v3 = gelu_f(acc1[mi][ni][3] + bv[3]);
            ss[mi] += (v0+v1)+(v2+v3);
            sq[mi] += (v0*v0+v1*v1)+(v2*v2+v3*v3);
            int off = r*128 + (((wcol*4 + ni*2 + (g>>1)) + r)&15)*8 + (g&1)*4;
            *(u32*)(Hl + off)     = pkbf(v0, v1);
            *(u32*)(Hl + off + 2) = pkbf(v2, v3);
          }
        }
        __syncthreads();
      }
    }

    // ---- fc2: 4 steps of BK=32 over this 128-hidden chunk ----
    #pragma unroll
    for (int u=0; u<4; ++u){
      if (u < 3){
        #pragma unroll
        for (int i=0;i<2;i++){
          int c = tid + i*512;
          int crow = c >> 2, s = c & 3, gs = (s - crow) & 3;
          glds16(w2 + (size_t)crow*1024 + n*128 + (u+1)*32 + gs*8,
                 Db + ((u+1)&1)*8192 + i*4096 + wave*512);
        }
      } else if (n < 7){
        #pragma unroll
        for (int i=0;i<2;i++){
          int c = tid + i*512;
          int hrow = c >> 3, s = c & 7, gs = (s - hrow) & 7;
          glds16(w1 + (size_t)((n+1)*128+hrow)*256 + gs*8,
                 Db + i*4096 + wave*512);               // slot0
        }
      }
      const u16* Bp = Db + (u&1)*8192;
      bf16x8 hf[4], bff[4];
      #pragma unroll
      for (int mi=0;mi<4;mi++){
        int r = wr*64 + mi*16 + lc16;
        hf[mi] = *(const bf16x8*)(Hl + r*128 + ((u*4 + g + r)&15)*8);
      }
      #pragma unroll
      for (int ni=0;ni<4;ni++){
        int cr = wcol*64 + ni*16 + lc16;
        bff[ni] = *(const bf16x8*)(Bp + cr*32 + ((g + cr)&3)*8);
      }
      #pragma unroll
      for (int mi=0;mi<4;mi++)
        #pragma unroll
        for (int ni=0;ni<4;ni++)
          acc2[mi][ni] = __builtin_amdgcn_mfma_f32_16x16x32_bf16(bff[ni], hf[mi], acc2[mi][ni], 0, 0, 0);
      asm volatile("s_waitcnt vmcnt(0)" ::: "memory");
      __builtin_amdgcn_s_barrier();
    }
  }

  // ---- LN3 stats reduce (g-groups via shfl, wcol waves via LDS) ----
  #pragma unroll
  for (int mi=0;mi<4;mi++){
    ss[mi] += __shfl_xor(ss[mi], 16, 64); ss[mi] += __shfl_xor(ss[mi], 32, 64);
    sq[mi] += __shfl_xor(sq[mi], 16, 64); sq[mi] += __shfl_xor(sq[mi], 32, 64);
  }
  float* sred = (float*)Hl;   // h dead
  if (g == 0){
    #pragma unroll
    for (int mi=0;mi<4;mi++){
      int r = wr*64 + mi*16 + lc16;
      sred[(wcol*128 + r)*2    ] = ss[mi];
      sred[(wcol*128 + r)*2 + 1] = sq[mi];
    }
  }
  __syncthreads();

  // ---- epilogue: LN3 fold + bf16-resid reconstruct + f32 out ----
  #pragma unroll
  for (int mi=0;mi<4;mi++){
    int r = wr*64 + mi*16 + lc16;
    int grow = m0 + r;
    float S = 0.f, Q = 0.f;
    #pragma unroll
    for (int wv=0; wv<4; ++wv){ S += sred[(wv*128 + r)*2]; Q += sred[(wv*128 + r)*2 + 1]; }
    float mean3 = S*(1.f/1024.f);
    float var3  = Q*(1.f/1024.f) - mean3*mean3;
    float rs = rsqrtf(var3 + 1e-5f);
    float mr = mean3 * rs;
    float mean2 = st2[2*grow];
    float istd2 = __builtin_amdgcn_rcpf(st2[2*grow+1]);
    #pragma unroll
    for (int ni=0;ni<4;ni++){
      int col = wcol*64 + ni*16 + g*4;
      f4 bv = *(const f4*)(b2 + col);
      f4 cw = *(const f4*)(colsum + col);
      f4 v;
      #pragma unroll
      for (int j=0;j<4;j++) v[j] = acc2[mi][ni][j]*rs - mr*cw[j] + bv[j];
      int aoff = r*256 + (((col>>3) + r)&31)*8 + (col&7);
      us4 xr = *(const us4*)(Al + aoff);
      #pragma unroll
      for (int j=0;j<4;j++) v[j] += bf2f(xr[j])*istd2 + mean2;
      *(f4*)(outv + (size_t)grow*256 + col) = v;
    }
  }
}

__global__ __launch_bounds__(128)
void attn_mfma_kernel(
    const u16* __restrict__ qkv,
    const u16* __restrict__ cmb,
    u16* __restrict__ outb)
{
  __shared__ u16 smem2[2][12288];
  int wave = threadIdx.x>>6, lane = threadIdx.x&63;
  int pairbase = blockIdx.x*4 + wave*2;
  int bw = pairbase>>3, h0 = pairbase&7, w = bw&63;
  int lc = lane&15, g = lane>>4;
  u16* S = &smem2[wave][0];
  const u16* qg0 = qkv + (size_t)pairbase*(WA*32);
  const u16* qg1 = qg0 + WA*32;
  const u16* kg0 = qg0 + (size_t)NPAIR*(WA*32);
  const u16* kg1 = kg0 + WA*32;
  const u16* vg0 = qg0 + (size_t)2*NPAIR*(WA*32);
  const u16* vg1 = vg0 + WA*32;

  #pragma unroll
  for (int i=0;i<4;i++){
    int idx = i*64 + lane;
    if (idx < 196){
      glds16(kg0 + idx*8, S + idx*8);
      glds16(kg1 + idx*8, S + 2048 + idx*8);
    }
  }
  us8 vv0[4], vv1[4];
  #pragma unroll
  for (int i=0;i<4;i++){
    int idx = i*64+lane; int r = idx>>2, seg = idx&3;
    if (r < WA){
      vv0[i] = *(const us8*)(vg0 + r*32 + seg*8);
      vv1[i] = *(const us8*)(vg1 + r*32 + seg*8);
    } else {
      #pragma unroll
      for (int e=0;e<8;e++){ vv0[i][e]=0; vv1[i][e]=0; }
    }
  }
  bf16x8 qa0[4], qa1[4];
  #pragma unroll
  for (int mi=0;mi<4;mi++){
    int r = mi*16 + lc;
    if (r < WA){
      qa0[mi] = *(const bf16x8*)(qg0 + r*32 + g*8);
      qa1[mi] = *(const bf16x8*)(qg1 + r*32 + g*8);
    } else {
      bf16x8 z;
      #pragma unroll
      for (int e=0;e<8;e++) z[e]=0;
      qa0[mi]=z; qa1[mi]=z;
    }
  }
  #pragma unroll
  for (int i=0;i<4;i++){
    int idx = i*64+lane; int r = idx>>2, seg = idx&3;
    #pragma unroll
    for (int e=0;e<8;e++){
      int d = seg*8 + e;
      u32 byte = ((u32)(d*128 + r*2)) ^ ((u32)(d&7)<<4);
      S[4096 + (byte>>1)] = vv0[i][e];
      S[6144 + (byte>>1)] = vv1[i][e];
    }
  }
  asm volatile("s_waitcnt vmcnt(0)" ::: "memory");
  __builtin_amdgcn_sched_barrier(0);

  u16* Pp = S + 8192;
  #pragma unroll
  for (int p=0; p<2; ++p){
    const u16* Kp = S + p*2048;
    const u16* Vp = S + 4096 + p*2048;
    const u16* cmbp = cmb + ((size_t)((w*8 + h0 + p)*49))*64;

    f32x4 acc[4][4];
    #pragma unroll
    for (int i=0;i<4;i++)
      #pragma unroll
      for (int j=0;j<4;j++){ acc[i][j][0]=0.f; acc[i][j][1]=0.f; acc[i][j][2]=0.f; acc[i][j][3]=0.f; }

    __builtin_amdgcn_s_setprio(1);
    #pragma unroll
    for (int ni=0;ni<4;ni++){
      bf16x8 kb = *(const bf16x8*)(Kp + (ni*16+lc)*32 + g*8);
      #pragma unroll
      for (int mi=0;mi<4;mi++)
        acc[mi][ni] = __builtin_amdgcn_mfma_f32_16x16x32_bf16(p==0 ? qa0[mi] : qa1[mi], kb, acc[mi][ni], 0, 0, 0);
    }
    __builtin_amdgcn_s_setprio(0);

    float rinv[4][4];
    #pragma unroll
    for (int mi=0;mi<4;mi++){
      #pragma unroll
      for (int jr=0;jr<4;jr++){
        int i = mi*16 + g*4 + jr;
        float sv[4];
        #pragma unroll
        for (int ni=0;ni<4;ni++){
          int j = ni*16 + lc;
          float s;
          if (i < WA && j < WA){
            s = acc[mi][ni][jr] + bf2f(cmbp[i*64 + j]);
          } else s = -1e9f;
          sv[ni] = s;
        }
        float mx = fmaxf(fmaxf(sv[0],sv[1]), fmaxf(sv[2],sv[3]));
        #pragma unroll
        for (int off=1; off<16; off<<=1) mx = fmaxf(mx, __shfl_xor(mx, off, 64));
        float sum = 0.f;
        #pragma unroll
        for (int ni=0;ni<4;ni++){ sv[ni] = __expf(sv[ni]-mx); sum += sv[ni]; }
        #pragma unroll
        for (int off=1; off<16; off<<=1) sum += __shfl_xor(sum, off, 64);
        rinv[mi][jr] = __builtin_amdgcn_rcpf(sum);
        #pragma unroll
        for (int ni=0;ni<4;ni++){
          int j = ni*16 + lc;
          u32 byte = ((u32)(i*128 + j*2)) ^ ((u32)(i&7)<<4);
          Pp[byte>>1] = f2bf(sv[ni]);
        }
      }
    }

    bf16x8 vb[2][2];
    #pragma unroll
    for (int kk=0;kk<2;kk++)
      #pragma unroll
      for (int ni=0;ni<2;ni++){
        int d = ni*16 + lc;
        u32 byte = ((u32)(d*128 + kk*64 + g*16)) ^ ((u32)(d&7)<<4);
        vb[kk][ni] = *(const bf16x8*)(Vp + (byte>>1));
      }
    f32x4 aco[4][2];
    #pragma unroll
    for (int i=0;i<4;i++)
      #pragma unroll
      for (int j=0;j<2;j++){ aco[i][j][0]=0.f; aco[i][j][1]=0.f; aco[i][j][2]=0.f; aco[i][j][3]=0.f; }
    __builtin_amdgcn_s_setprio(1);
    #pragma unroll
    for (int mi=0;mi<4;mi++){
      int r = mi*16 + lc;
      #pragma unroll
      for (int kk=0;kk<2;kk++){
        u32 byte = ((u32)(r*128 + kk*64 + g*16)) ^ ((u32)(r&7)<<4);
        bf16x8 pa = *(const bf16x8*)(Pp + (byte>>1));
        #pragma unroll
        for (int ni=0;ni<2;ni++)
          aco[mi][ni] = __builtin_amdgcn_mfma_f32_16x16x32_bf16(pa, vb[kk][ni], aco[mi][ni], 0, 0, 0);
      }
    }
    __builtin_amdgcn_s_setprio(0);

    u16* Op = S + p*2048;
    #pragma unroll
    for (int mi=0;mi<4;mi++){
      #pragma unroll
      for (int jr=0;jr<4;jr++){
        int i = mi*16 + g*4 + jr;
        if (i < WA){
          float rv = rinv[mi][jr];
          #pragma unroll
          for (int ni=0;ni<2;ni++)
            Op[i*32 + ni*16 + lc] = f2bf(aco[mi][ni][jr]*rv);
        }
      }
    }
    size_t obase = (size_t)(bw*WA)*256 + (h0+p)*32;
    #pragma unroll
    for (int i=0;i<4;i++){
      int c = i*64 + lane;
      if (c < WA*4){
        int t = c>>2, seg = c&3;
        *(us8*)(outb + obase + (size_t)t*256 + seg*8) = *(const us8*)(Op + t*32 + seg*8);
      }
    }
  }
}

extern "C" void kernel_launch(void* const* d_in, const int* in_sizes, int n_in,
                              void* d_out, int out_size, void* d_ws, size_t ws_size,
                              hipStream_t stream) {
  const float* x      = (const float*)d_in[0];
  const float* ln1w   = (const float*)d_in[1];
  const float* ln1b   = (const float*)d_in[2];
  const float* qkv_w  = (const float*)d_in[3];
  const float* qkv_b  = (const float*)d_in[4];
  const float* rpb    = (const float*)d_in[5];
  const float* proj_w = (const float*)d_in[6];
  const float* proj_b = (const float*)d_in[7];
  const float* ln2w   = (const float*)d_in[8];
  const float* ln2b   = (const float*)d_in[9];
  const float* fc1_w  = (const float*)d_in[10];
  const float* fc1_b  = (const float*)d_in[11];
  const float* ln3w   = (const float*)d_in[12];
  const float* ln3b   = (const float*)d_in[13];
  const float* fc2_w  = (const float*)d_in[14];
  const float* fc2_b  = (const float*)d_in[15];
  const float* amask  = (const float*)d_in[16];
  const int*   rel    = (const int*)d_in[17];
  float* out = (float*)d_out;

  char* ws = (char*)d_ws;
  float* hstats = (float*)(ws);
  float* stats2 = (float*)(ws +  802816);
  float* bq     = (float*)(ws + 1605632);
  float* b1     = (float*)(ws + 1608704);
  float* b2     = (float*)(ws + 1612800);
  float* bp     = (float*)(ws + 1613824);
  float* cs2    = (float*)(ws + 1614848);
  u16*   wq     = (u16*)  (ws + 1615872);
  u16*   w1     = (u16*)  (ws + 2009088);
  u16*   w2     = (u16*)  (ws + 2533376);
  u16*   wp     = (u16*)  (ws + 3057664);
  const size_t P0 = 3188736;
  u16*   qkvbuf = (u16*)(ws + P0);
  u16*   attno  = (u16*)(ws + P0 + 154140672);
  u16*   xb     = (u16*)(ws + P0 + 154140672);
  u16*   ob     = (u16*)(ws + P0);
  u16*   x1b    = (u16*)(ws + P0 + 205520896);
  u16*   cmb    = (u16*)(ws + P0 + 205520896);
  const int bigws = (ws_size >= (size_t)(P0 + 205520896ull + 51380224ull));

  prep_weights<<<576,256,0,stream>>>(qkv_w,qkv_b,ln1w,ln1b, fc1_w,fc1_b,ln2w,ln2b,
                                     fc2_w,fc2_b,ln3w,ln3b, proj_w,proj_b,
                                     wq,bq, w1,b1, w2,b2, wp,bp, cs2, hstats);
  cmb_kernel<<<1568,256,0,stream>>>(rpb, rel, amask, cmb);
  ln_apply_kernel<<<NTOK/4,256,0,stream>>>(x, xb);
  gemm18<0,0,0,2><<<784*6,256,0,stream>>>(xb, wq, nullptr, nullptr, bq, nullptr, nullptr, qkvbuf, 256, 6, 588);
  attn_mfma_kernel<<<NPAIR/4,128,0,stream>>>(qkvbuf, cmb, attno);
  if (bigws){
    gemm18<1,5,1,2><<<784*2,256,0,stream>>>(attno, wp, nullptr, nullptr, bp, x, nullptr, ob, 256, 2, 196);
    ln_apply_b_kernel<<<NTOK/4,256,0,stream>>>(ob, x1b, stats2);
    mlp_fused<<<784,512,0,stream>>>(x1b, w1, w2, b1, b2, cs2, stats2, out);
  } else {
    gemm18<1,1,1,2><<<784*2,256,0,stream>>>(attno, wp, nullptr, nullptr, bp, x, nullptr, out, 256, 2, 196);
    ln_stats_kernel<256,0><<<NTOK/4,256,0,stream>>>(out, stats2);
    gemm18<3,2,1,2><<<784*8,256,0,stream>>>(out, w1, stats2, hstats, b1, nullptr, nullptr, (u16*)(ws+P0), 256, 8, 784);
    gemm18<1,4,1,2><<<784*2,256,0,stream>>>((u16*)(ws+P0), w2, hstats, nullptr, b2, out, cs2, out, 1024, 2, 196);
  }
}